// Round 6
// baseline (29.547 us; speedup 1.0000x reference)
//
#include <hip/hip_runtime.h>
#include <math.h>

// Graph2GraphModel: lidar-chain GCN (3 layers, HID=64) -> masked mean pool
// -> Wp(64x512) -> relu(Wm1 512x1024) -> Wm2(1024x200).
//
// Round-6 structure (lesson: k2's redundant per-block Wp read (128KB) was the
// serial long pole). Algebra: m1 = relu(gemb @ (Wp@Wm1) + (bp@Wm1 + bm1)).
//  k1 (124 blocks): blocks 0-59 GCN halo chunks -> partial pool + mask cnt;
//     blocks 60-123 compute A^T = (Wp@Wm1)^T slices (16 cols each) + aa.
//     Block 0 inits out = bm2 (graph-ordered before k2 => replay-safe).
//  k2 (64 blocks): gemb + m1 slice from 4KB A^T slice (prefetched) +
//     atomicAdd of (m1_slice @ Wm2_rows) into out.

#define NSCAN 360
#define HID 64
#define NB1 60      // GCN blocks
#define CHUNK 6     // nodes per GCN block
#define EXT 12      // CHUNK + 6 halo
#define NBA 64      // A-precompute blocks (16 cols each)
#define NB2 64      // k2 blocks

// ws float offsets
#define WSF_PARTIAL 0                    // 60*64
#define WSF_CNT     3840                 // 60
#define WSF_AT      3904                 // 1024*64 (A transposed [j][r])
#define WSF_AA      69440                // 1024

__device__ __forceinline__ void matmul64(int t, int glo, int ghi, int base,
                                         const float (*sh)[HID],
                                         float (*shw)[HID],
                                         const float (*sW)[HID]) {
  const int cnt = ghi - glo;
  const int off = glo - base;
  if (t < cnt * 16) {
    const int nl = off + (t >> 4);
    const int j4 = (t & 15) << 2;
    float a0 = 0.f, a1 = 0.f, a2 = 0.f, a3 = 0.f;
#pragma unroll 16
    for (int k = 0; k < HID; ++k) {
      const float hv = sh[nl][k];
      const float4 w = *reinterpret_cast<const float4*>(&sW[k][j4]);
      a0 = fmaf(hv, w.x, a0);
      a1 = fmaf(hv, w.y, a1);
      a2 = fmaf(hv, w.z, a2);
      a3 = fmaf(hv, w.w, a3);
    }
    float4 r; r.x = a0; r.y = a1; r.z = a2; r.w = a3;
    *reinterpret_cast<float4*>(&shw[nl][j4]) = r;
  }
}

__device__ __forceinline__ void agg_relu(int t, int olo, int ohi, int base,
                                         const float (*shw)[HID],
                                         float (*sh)[HID],
                                         const float* linv,
                                         const float* lcoef,
                                         const float* __restrict__ bias) {
  const int cnt = ohi - olo;
  for (int o = t; o < cnt * HID; o += 256) {
    const int nl = (o >> 6) + (olo - base), j = o & 63;
    const int n = base + nl;
    float v = linv[nl] * linv[nl] * shw[nl][j];
    if (n > 0)         v += lcoef[nl - 1] * shw[nl - 1][j];
    if (n < NSCAN - 1) v += lcoef[nl]     * shw[nl + 1][j];
    v += bias[j];
    sh[nl][j] = fmaxf(v, 0.f);
  }
}

__global__ __launch_bounds__(256) void k1_gcn(
    const float* __restrict__ x,
    const float* __restrict__ W1, const float* __restrict__ b1,
    const float* __restrict__ W2, const float* __restrict__ b2,
    const float* __restrict__ W3, const float* __restrict__ b3,
    const float* __restrict__ Wp, const float* __restrict__ bp,
    const float* __restrict__ Wm1, const float* __restrict__ bm1,
    const float* __restrict__ bm2,
    float* __restrict__ ws, float* __restrict__ out) {
  __shared__ float lmask[EXT + 2];
  __shared__ float linv[EXT];
  __shared__ float lcoef[EXT];
  __shared__ float snod[EXT][2];
  __shared__ float sh[EXT][HID];
  __shared__ float shw[EXT][HID];
  __shared__ float sW[HID][HID];
  __shared__ float sred[4][HID];
  __shared__ float sWp[64][129];   // A-path k-tile of Wp (pad->2-way, free)
  __shared__ float sbp[128];

  const int t = threadIdx.x;
  const int b = blockIdx.x;

  if (b >= NB1) {
    // ---------------- A-precompute path: A^T slice + aa ----------------
    const int ab = b - NB1;            // 0..63, cols j0 = ab*16
    const int g = t >> 6, r = t & 63;  // wave g handles cols j0+4g..+3
    const float4* wrow = reinterpret_cast<const float4*>(Wm1) + ab * 4 + g;
    float4 acc  = {0.f, 0.f, 0.f, 0.f};
    float4 aacc = {0.f, 0.f, 0.f, 0.f};
    for (int kt = 0; kt < 512; kt += 128) {
      for (int i = t; i < 64 * 128; i += 256) {
        const int row = i >> 7, kk = i & 127;
        sWp[row][kk] = Wp[row * 512 + kt + kk];
      }
      if (t < 128) sbp[t] = bp[kt + t];
      __syncthreads();
#pragma unroll 8
      for (int kk = 0; kk < 128; ++kk) {
        const float4 w = wrow[(kt + kk) * 256];   // wave-uniform broadcast
        const float a = sWp[r][kk];
        const float bpv = sbp[kk];
        acc.x  = fmaf(a,   w.x, acc.x);
        acc.y  = fmaf(a,   w.y, acc.y);
        acc.z  = fmaf(a,   w.z, acc.z);
        acc.w  = fmaf(a,   w.w, acc.w);
        aacc.x = fmaf(bpv, w.x, aacc.x);
        aacc.y = fmaf(bpv, w.y, aacc.y);
        aacc.z = fmaf(bpv, w.z, aacc.z);
        aacc.w = fmaf(bpv, w.w, aacc.w);
      }
      __syncthreads();
    }
    float* At = ws + WSF_AT;
    float* aa = ws + WSF_AA;
    const int jb = ab * 16 + g * 4;
    At[(jb + 0) * 64 + r] = acc.x;     // coalesced 256B per wave per col
    At[(jb + 1) * 64 + r] = acc.y;
    At[(jb + 2) * 64 + r] = acc.z;
    At[(jb + 3) * 64 + r] = acc.w;
    if (r == 0) {
      aa[jb + 0] = aacc.x + bm1[jb + 0];
      aa[jb + 1] = aacc.y + bm1[jb + 1];
      aa[jb + 2] = aacc.z + bm1[jb + 2];
      aa[jb + 3] = aacc.w + bm1[jb + 3];
    }
    return;
  }

  // ---------------- GCN path (round-5 proven) ----------------
  float* partial = ws + WSF_PARTIAL;

  // out = bm2 each call (block 0; k2 atomicAdds on top, graph-ordered)
  if (b == 0 && t < 200) out[t] = bm2[t];

  const int s = b * CHUNK, e = s + CHUNK;
  const int lo3 = max(0, s - 3), hi3 = min(NSCAN, e + 3);
  const int lo2 = max(0, s - 2), hi2 = min(NSCAN, e + 2);
  const int lo1 = max(0, s - 1), hi1 = min(NSCAN, e + 1);
  const int base = lo3;

  // ---- P0: mask window (wave0), trig nodes (wave1), W2 stage (waves2-3) ----
  if (t < EXT + 2) {
    const int gi = base - 1 + t;
    lmask[t] = (gi >= 0 && gi < NSCAN && x[gi] != 1.0f) ? 1.f : 0.f;
  } else if (t >= 64 && t < 64 + EXT) {
    const int l = t - 64, gi = base + l;
    if (gi < hi3) {
      const float lv = x[gi];
      const double a = (double)gi * (6.283185307179586476925287 / 359.0);
      snod[l][0] = lv * (float)cos(a);
      snod[l][1] = lv * (float)sin(a);
    }
  }
  if (t >= 128) {
    const float4* src = reinterpret_cast<const float4*>(W2);
    float4* dst = reinterpret_cast<float4*>(&sW[0][0]);
    for (int i = t - 128; i < 1024; i += 128) dst[i] = src[i];
  }
  __syncthreads();

  // ---- P1: inv -> coef (wave0) ; layer-1 matmul (waves 1-3) ----
  if (t < 64) {
    if (t < EXT && base + t < hi3) {
      const float m = lmask[t + 1];
      const float deg = m * (1.f + lmask[t] + lmask[t + 2]);
      linv[t] = (deg > 0.f) ? 1.0f / sqrtf(deg) : 0.f;
    }
    __builtin_amdgcn_wave_barrier();
    if (t < EXT - 1 && base + t < min(NSCAN - 1, hi3 - 1)) {
      const float pair = lmask[t + 1] * lmask[t + 2];
      lcoef[t] = pair * linv[t] * linv[t + 1];
    }
  } else {
    for (int o = t - 64; o < (hi3 - lo3) * HID; o += 192) {
      const int nl = o >> 6, j = o & 63;
      shw[nl][j] = fmaf(snod[nl][0], W1[j], snod[nl][1] * W1[HID + j]);
    }
  }
  __syncthreads();

  agg_relu(t, lo2, hi2, base, shw, sh, linv, lcoef, b1);
  __syncthreads();
  matmul64(t, lo2, hi2, base, sh, shw, sW);
  __syncthreads();
  agg_relu(t, lo1, hi1, base, shw, sh, linv, lcoef, b2);
  {
    const float4* src = reinterpret_cast<const float4*>(W3);
    float4* dst = reinterpret_cast<float4*>(&sW[0][0]);
    for (int i = t; i < 1024; i += 256) dst[i] = src[i];
  }
  __syncthreads();
  matmul64(t, lo1, hi1, base, sh, shw, sW);
  __syncthreads();
  agg_relu(t, s, e, base, shw, sh, linv, lcoef, b3);
  __syncthreads();

  // ---- masked pool over own chunk + local mask count ----
  {
    const int jl = t & 63, g = t >> 6;
    float acc = 0.f;
    for (int n = s + g; n < e; n += 4)
      acc += sh[n - base][jl] * lmask[n - base + 1];
    sred[g][jl] = acc;
  }
  __syncthreads();
  if (t < HID)
    partial[b * HID + t] = sred[0][t] + sred[1][t] + sred[2][t] + sred[3][t];
  if (t == 0) {
    float cs = 0.f;
#pragma unroll
    for (int i = 0; i < CHUNK; ++i) cs += lmask[s - base + 1 + i];
    ws[WSF_CNT + b] = cs;
  }
}

__global__ __launch_bounds__(256) void k2_mlp(
    const float* __restrict__ ws, const float* __restrict__ Wm2,
    float* __restrict__ out) {
  __shared__ float sgemb[64];
  __shared__ float sm1[16];
  __shared__ float snv;
  const int t = threadIdx.x;
  const int b = blockIdx.x;
  const float* partial = ws + WSF_PARTIAL;
  const float* cnt     = ws + WSF_CNT;
  const float* At      = ws + WSF_AT;
  const float* aa      = ws + WSF_AA;

  const int g = t >> 6, r = t & 63;
  const int jb = b * 16 + g * 4;

  // prefetch everything independent of gemb BEFORE the barrier
  const float a0 = At[(jb + 0) * 64 + r];
  const float a1 = At[(jb + 1) * 64 + r];
  const float a2 = At[(jb + 2) * 64 + r];
  const float a3 = At[(jb + 3) * 64 + r];
  const float av0 = aa[jb + 0], av1 = aa[jb + 1];
  const float av2 = aa[jb + 2], av3 = aa[jb + 3];
  float wv[16];
  if (t < 200) {
#pragma unroll
    for (int rr = 0; rr < 16; ++rr) wv[rr] = Wm2[(b * 16 + rr) * 200 + t];
  }

  float gsum = 0.f;
  if (t < 64) {
#pragma unroll
    for (int bb = 0; bb < NB1; ++bb) gsum += partial[bb * 64 + t];
  } else if (t < 128) {
    const int l = t - 64;
    float cv = (l < NB1) ? cnt[l] : 0.f;
    for (int off = 32; off; off >>= 1) cv += __shfl_down(cv, off, 64);
    if (l == 0) snv = cv;
  }
  __syncthreads();
  if (t < 64) sgemb[t] = gsum / snv;
  __syncthreads();

  // m1 slice: 4 cols per wave, cross-lane reduce
  {
    const float ge = sgemb[r];
    float p0 = a0 * ge, p1 = a1 * ge, p2 = a2 * ge, p3 = a3 * ge;
    for (int off = 32; off; off >>= 1) {
      p0 += __shfl_down(p0, off, 64);
      p1 += __shfl_down(p1, off, 64);
      p2 += __shfl_down(p2, off, 64);
      p3 += __shfl_down(p3, off, 64);
    }
    if (r == 0) {
      sm1[g * 4 + 0] = fmaxf(p0 + av0, 0.f);
      sm1[g * 4 + 1] = fmaxf(p1 + av1, 0.f);
      sm1[g * 4 + 2] = fmaxf(p2 + av2, 0.f);
      sm1[g * 4 + 3] = fmaxf(p3 + av3, 0.f);
    }
  }
  __syncthreads();

  // out contribution from this block's 16 m1 entries (Wm2 rows in regs)
  if (t < 200) {
    float acc = 0.f;
#pragma unroll
    for (int rr = 0; rr < 16; ++rr) acc = fmaf(sm1[rr], wv[rr], acc);
    atomicAdd(&out[t], acc);
  }
}

extern "C" void kernel_launch(void* const* d_in, const int* in_sizes, int n_in,
                              void* d_out, int out_size, void* d_ws,
                              size_t ws_size, hipStream_t stream) {
  const float* x   = (const float*)d_in[0];
  const float* W1  = (const float*)d_in[1];
  const float* b1  = (const float*)d_in[2];
  const float* W2  = (const float*)d_in[3];
  const float* b2  = (const float*)d_in[4];
  const float* W3  = (const float*)d_in[5];
  const float* b3  = (const float*)d_in[6];
  const float* Wp  = (const float*)d_in[7];
  const float* bp  = (const float*)d_in[8];
  const float* Wm1 = (const float*)d_in[9];
  const float* bm1 = (const float*)d_in[10];
  const float* Wm2 = (const float*)d_in[11];
  const float* bm2 = (const float*)d_in[12];

  float* ws  = (float*)d_ws;
  float* out = (float*)d_out;

  k1_gcn<<<NB1 + NBA, 256, 0, stream>>>(x, W1, b1, W2, b2, W3, b3,
                                        Wp, bp, Wm1, bm1, bm2, ws, out);
  k2_mlp<<<NB2, 256, 0, stream>>>(ws, Wm2, out);
}

// Round 7
// 21.113 us; speedup vs baseline: 1.3994x; 1.3994x over previous
//
#include <hip/hip_runtime.h>
#include <math.h>

// Graph2GraphModel: lidar-chain GCN (3 layers, HID=64) -> masked mean pool
// -> Wp(64x512) -> relu(Wm1 512x1024) -> Wm2(1024x200).
//
// Round-7: revert round-6's A-precompute (67 MFLOP >> 8.8 MFLOP GCN; big
// regression). Round-5 2-node structure + targeted path cuts:
//  k1 (60 blocks): GCN halo chunks -> partial pool + per-block mask count;
//     block 0 inits out = bm2 (graph-ordered before k2 => replay-safe).
//     f32 sincosf instead of f64 cos/sin (software f64 was on the P0 path).
//  k2 (64 blocks): wave0 gemb+n_valid  ||  waves1-3 stage Wp->LDS (128KB);
//     then c from LDS, 16-col m1 slice, atomicAdd (m1_slice @ Wm2) into out.
//     Wm2 rows / bm1 / bp prefetched to registers at kernel start.

#define NSCAN 360
#define HID 64
#define NB1 60      // GCN blocks
#define CHUNK 6     // nodes per GCN block
#define EXT 12      // CHUNK + 6 halo
#define NB2 64      // k2 blocks (16 m1 cols each)

// ws float offsets
#define WSF_PARTIAL 0                    // 60*64
#define WSF_CNT     3840                 // 60

__device__ __forceinline__ void matmul64(int t, int glo, int ghi, int base,
                                         const float (*sh)[HID],
                                         float (*shw)[HID],
                                         const float (*sW)[HID]) {
  const int cnt = ghi - glo;
  const int off = glo - base;
  if (t < cnt * 16) {
    const int nl = off + (t >> 4);
    const int j4 = (t & 15) << 2;
    float a0 = 0.f, a1 = 0.f, a2 = 0.f, a3 = 0.f;
#pragma unroll 16
    for (int k = 0; k < HID; ++k) {
      const float hv = sh[nl][k];
      const float4 w = *reinterpret_cast<const float4*>(&sW[k][j4]);
      a0 = fmaf(hv, w.x, a0);
      a1 = fmaf(hv, w.y, a1);
      a2 = fmaf(hv, w.z, a2);
      a3 = fmaf(hv, w.w, a3);
    }
    float4 r; r.x = a0; r.y = a1; r.z = a2; r.w = a3;
    *reinterpret_cast<float4*>(&shw[nl][j4]) = r;
  }
}

__device__ __forceinline__ void agg_relu(int t, int olo, int ohi, int base,
                                         const float (*shw)[HID],
                                         float (*sh)[HID],
                                         const float* linv,
                                         const float* lcoef,
                                         const float* __restrict__ bias) {
  const int cnt = ohi - olo;
  for (int o = t; o < cnt * HID; o += 256) {
    const int nl = (o >> 6) + (olo - base), j = o & 63;
    const int n = base + nl;
    float v = linv[nl] * linv[nl] * shw[nl][j];
    if (n > 0)         v += lcoef[nl - 1] * shw[nl - 1][j];
    if (n < NSCAN - 1) v += lcoef[nl]     * shw[nl + 1][j];
    v += bias[j];
    sh[nl][j] = fmaxf(v, 0.f);
  }
}

__global__ __launch_bounds__(256) void k1_gcn(
    const float* __restrict__ x,
    const float* __restrict__ W1, const float* __restrict__ b1,
    const float* __restrict__ W2, const float* __restrict__ b2,
    const float* __restrict__ W3, const float* __restrict__ b3,
    const float* __restrict__ bm2,
    float* __restrict__ ws, float* __restrict__ out) {
  __shared__ float lmask[EXT + 2];
  __shared__ float linv[EXT];
  __shared__ float lcoef[EXT];
  __shared__ float snod[EXT][2];
  __shared__ float sh[EXT][HID];
  __shared__ float shw[EXT][HID];
  __shared__ float sW[HID][HID];
  __shared__ float sred[4][HID];

  const int t = threadIdx.x;
  const int b = blockIdx.x;
  float* partial = ws + WSF_PARTIAL;

  // out = bm2 each call (block 0; k2 atomicAdds on top, graph-ordered)
  if (b == 0 && t < 200) out[t] = bm2[t];

  const int s = b * CHUNK, e = s + CHUNK;
  const int lo3 = max(0, s - 3), hi3 = min(NSCAN, e + 3);
  const int lo2 = max(0, s - 2), hi2 = min(NSCAN, e + 2);
  const int lo1 = max(0, s - 1), hi1 = min(NSCAN, e + 1);
  const int base = lo3;

  // ---- P0: mask window (wave0), trig nodes (wave1, f32), W2 (waves2-3) ----
  if (t < EXT + 2) {
    const int gi = base - 1 + t;
    lmask[t] = (gi >= 0 && gi < NSCAN && x[gi] != 1.0f) ? 1.f : 0.f;
  } else if (t >= 64 && t < 64 + EXT) {
    const int l = t - 64, gi = base + l;
    if (gi < hi3) {
      const float lv = x[gi];
      const float a = (float)((double)gi * (6.283185307179586476925287 / 359.0));
      float sn, cs;
      sincosf(a, &sn, &cs);
      snod[l][0] = lv * cs;
      snod[l][1] = lv * sn;
    }
  }
  if (t >= 128) {
    const float4* src = reinterpret_cast<const float4*>(W2);
    float4* dst = reinterpret_cast<float4*>(&sW[0][0]);
    for (int i = t - 128; i < 1024; i += 128) dst[i] = src[i];
  }
  __syncthreads();

  // ---- P1: inv -> coef (wave0) ; layer-1 matmul (waves 1-3) ----
  if (t < 64) {
    if (t < EXT && base + t < hi3) {
      const float m = lmask[t + 1];
      const float deg = m * (1.f + lmask[t] + lmask[t + 2]);
      linv[t] = (deg > 0.f) ? 1.0f / sqrtf(deg) : 0.f;
    }
    __builtin_amdgcn_wave_barrier();
    if (t < EXT - 1 && base + t < min(NSCAN - 1, hi3 - 1)) {
      const float pair = lmask[t + 1] * lmask[t + 2];
      lcoef[t] = pair * linv[t] * linv[t + 1];
    }
  } else {
    for (int o = t - 64; o < (hi3 - lo3) * HID; o += 192) {
      const int nl = o >> 6, j = o & 63;
      shw[nl][j] = fmaf(snod[nl][0], W1[j], snod[nl][1] * W1[HID + j]);
    }
  }
  __syncthreads();

  agg_relu(t, lo2, hi2, base, shw, sh, linv, lcoef, b1);
  __syncthreads();
  matmul64(t, lo2, hi2, base, sh, shw, sW);
  __syncthreads();
  agg_relu(t, lo1, hi1, base, shw, sh, linv, lcoef, b2);
  {
    const float4* src = reinterpret_cast<const float4*>(W3);
    float4* dst = reinterpret_cast<float4*>(&sW[0][0]);
    for (int i = t; i < 1024; i += 256) dst[i] = src[i];
  }
  __syncthreads();
  matmul64(t, lo1, hi1, base, sh, shw, sW);
  __syncthreads();
  agg_relu(t, s, e, base, shw, sh, linv, lcoef, b3);
  __syncthreads();

  // ---- masked pool over own chunk + per-block mask count ----
  {
    const int jl = t & 63, g = t >> 6;
    float acc = 0.f;
    for (int n = s + g; n < e; n += 4)
      acc += sh[n - base][jl] * lmask[n - base + 1];
    sred[g][jl] = acc;
  }
  __syncthreads();
  if (t < HID)
    partial[b * HID + t] = sred[0][t] + sred[1][t] + sred[2][t] + sred[3][t];
  if (t == 0) {
    float cs = 0.f;
#pragma unroll
    for (int i = 0; i < CHUNK; ++i) cs += lmask[s - base + 1 + i];
    ws[WSF_CNT + b] = cs;
  }
}

__global__ __launch_bounds__(256) void k2_mlp(
    const float* __restrict__ Wp, const float* __restrict__ bp,
    const float* __restrict__ Wm1, const float* __restrict__ bm1,
    const float* __restrict__ Wm2,
    const float* __restrict__ ws, float* __restrict__ out) {
  __shared__ float sWp[HID][512];   // 128 KB (gfx950 allows >64KB static LDS)
  __shared__ float sc[512];
  __shared__ float sgemb[HID];
  __shared__ float4 swred[4][4];
  __shared__ float sm1[16];

  const int t = threadIdx.x;
  const int b = blockIdx.x;
  const float* partial = ws + WSF_PARTIAL;
  const float* cnt     = ws + WSF_CNT;

  // ---- top prefetches (independent of gemb) ----
  float wv[16];
  if (t < 200) {
#pragma unroll
    for (int rr = 0; rr < 16; ++rr) wv[rr] = Wm2[(b * 16 + rr) * 200 + t];
  }
  const float bp0 = bp[t], bp1 = bp[t + 256];
  float4 bb4 = {0.f, 0.f, 0.f, 0.f};
  if (t < 4) bb4 = reinterpret_cast<const float4*>(bm1)[b * 4 + t];

  if (t < 64) {
    // wave0: gemb + n_valid (cnt produced by k1)
    float gsum = 0.f;
#pragma unroll
    for (int bb = 0; bb < NB1; ++bb) gsum += partial[bb * HID + t];
    float cv = (t < NB1) ? cnt[t] : 0.f;
    for (int off = 32; off; off >>= 1) cv += __shfl_down(cv, off, 64);
    const float nv = __shfl(cv, 0, 64);
    sgemb[t] = gsum / nv;
  } else {
    // waves 1-3: stage Wp -> LDS (8192 float4 over 192 threads)
    const float4* src = reinterpret_cast<const float4*>(Wp);
    float4* dst = reinterpret_cast<float4*>(&sWp[0][0]);
    for (int i = t - 64; i < 8192; i += 192) dst[i] = src[i];
  }
  __syncthreads();

  // ---- c = gemb @ Wp + bp (from LDS; cols t and t+256) ----
  {
    float acc0 = bp0, acc1 = bp1;
#pragma unroll 16
    for (int k = 0; k < HID; ++k) {
      const float ge = sgemb[k];
      acc0 = fmaf(ge, sWp[k][t], acc0);
      acc1 = fmaf(ge, sWp[k][t + 256], acc1);
    }
    sc[t] = acc0;
    sc[t + 256] = acc1;
  }
  __syncthreads();

  // ---- m1 slice: 16 cols (4 float4-chunks), k split over 64 groups ----
  {
    const int c4 = t & 3;          // float4 col chunk
    const int g  = t >> 2;         // 64 k-groups of 8
    const float4* wvv = reinterpret_cast<const float4*>(Wm1) + b * 4 + c4;
    float4 a4; a4.x = 0.f; a4.y = 0.f; a4.z = 0.f; a4.w = 0.f;
    const int k0 = g * 8;
#pragma unroll 8
    for (int ki = 0; ki < 8; ++ki) {
      const float cvv = sc[k0 + ki];
      const float4 w = wvv[(k0 + ki) * 256];
      a4.x = fmaf(cvv, w.x, a4.x);
      a4.y = fmaf(cvv, w.y, a4.y);
      a4.z = fmaf(cvv, w.z, a4.z);
      a4.w = fmaf(cvv, w.w, a4.w);
    }
#pragma unroll
    for (int off = 4; off < 64; off <<= 1) {
      a4.x += __shfl_down(a4.x, off, 64);
      a4.y += __shfl_down(a4.y, off, 64);
      a4.z += __shfl_down(a4.z, off, 64);
      a4.w += __shfl_down(a4.w, off, 64);
    }
    if ((t & 63) < 4) swred[t >> 6][t & 63] = a4;
  }
  __syncthreads();
  if (t < 4) {
    float4 v = swred[0][t];
    const float4 v1 = swred[1][t], v2 = swred[2][t], v3 = swred[3][t];
    v.x += v1.x + v2.x + v3.x;
    v.y += v1.y + v2.y + v3.y;
    v.z += v1.z + v2.z + v3.z;
    v.w += v1.w + v2.w + v3.w;
    float4 r;
    r.x = fmaxf(v.x + bb4.x, 0.f);
    r.y = fmaxf(v.y + bb4.y, 0.f);
    r.z = fmaxf(v.z + bb4.z, 0.f);
    r.w = fmaxf(v.w + bb4.w, 0.f);
    reinterpret_cast<float4*>(sm1)[t] = r;
  }
  __syncthreads();

  // ---- out contribution (Wm2 rows already in regs) ----
  if (t < 200) {
    float acc = 0.f;
#pragma unroll
    for (int rr = 0; rr < 16; ++rr) acc = fmaf(sm1[rr], wv[rr], acc);
    atomicAdd(&out[t], acc);
  }
}

extern "C" void kernel_launch(void* const* d_in, const int* in_sizes, int n_in,
                              void* d_out, int out_size, void* d_ws,
                              size_t ws_size, hipStream_t stream) {
  const float* x   = (const float*)d_in[0];
  const float* W1  = (const float*)d_in[1];
  const float* b1  = (const float*)d_in[2];
  const float* W2  = (const float*)d_in[3];
  const float* b2  = (const float*)d_in[4];
  const float* W3  = (const float*)d_in[5];
  const float* b3  = (const float*)d_in[6];
  const float* Wp  = (const float*)d_in[7];
  const float* bp  = (const float*)d_in[8];
  const float* Wm1 = (const float*)d_in[9];
  const float* bm1 = (const float*)d_in[10];
  const float* Wm2 = (const float*)d_in[11];
  const float* bm2 = (const float*)d_in[12];

  float* ws  = (float*)d_ws;
  float* out = (float*)d_out;

  k1_gcn<<<NB1, 256, 0, stream>>>(x, W1, b1, W2, b2, W3, b3, bm2, ws, out);
  k2_mlp<<<NB2, 256, 0, stream>>>(Wp, bp, Wm1, bm1, Wm2, ws, out);
}

// Round 8
// 17.867 us; speedup vs baseline: 1.6537x; 1.1817x over previous
//
#include <hip/hip_runtime.h>
#include <math.h>

// Graph2GraphModel: lidar-chain GCN (3 layers, HID=64) -> masked mean pool
// -> Wp(64x512) -> relu(Wm1 512x1024) -> Wm2(1024x200).
//
// R8 = R5 proven 2-node structure + three micro-opts (R7 post-mortem:
// the 128KB Wp->LDS staging was the regression -- occupancy 1 and a serial
// pre-barrier staging loop; removed):
//  - k2 prefetches Wm2 rows / bm1 / bp into registers at kernel start
//  - k2 uses k1-produced mask counts (no x re-read)
//  - k1 trig via hardware __sinf/__cosf (f64 cos/sin was on the P0 path)
//  k1 (60 blocks): GCN halo chunks -> partial pool + per-block mask count;
//     block 0 inits out = bm2 (graph-ordered before k2 => replay-safe).
//  k2 (64 blocks): wave0 gemb; c = gemb@Wp+bp direct from global (L2);
//     16-col m1 slice; atomicAdd (m1_slice @ Wm2 rows) into out.

#define NSCAN 360
#define HID 64
#define NB1 60      // GCN blocks
#define CHUNK 6     // nodes per GCN block
#define EXT 12      // CHUNK + 6 halo
#define NB2 64      // k2 blocks (16 m1 cols each)

// ws float offsets
#define WSF_PARTIAL 0                    // 60*64
#define WSF_CNT     3840                 // 60

__device__ __forceinline__ void matmul64(int t, int glo, int ghi, int base,
                                         const float (*sh)[HID],
                                         float (*shw)[HID],
                                         const float (*sW)[HID]) {
  const int cnt = ghi - glo;
  const int off = glo - base;
  if (t < cnt * 16) {
    const int nl = off + (t >> 4);
    const int j4 = (t & 15) << 2;
    float a0 = 0.f, a1 = 0.f, a2 = 0.f, a3 = 0.f;
#pragma unroll 16
    for (int k = 0; k < HID; ++k) {
      const float hv = sh[nl][k];
      const float4 w = *reinterpret_cast<const float4*>(&sW[k][j4]);
      a0 = fmaf(hv, w.x, a0);
      a1 = fmaf(hv, w.y, a1);
      a2 = fmaf(hv, w.z, a2);
      a3 = fmaf(hv, w.w, a3);
    }
    float4 r; r.x = a0; r.y = a1; r.z = a2; r.w = a3;
    *reinterpret_cast<float4*>(&shw[nl][j4]) = r;
  }
}

__device__ __forceinline__ void agg_relu(int t, int olo, int ohi, int base,
                                         const float (*shw)[HID],
                                         float (*sh)[HID],
                                         const float* linv,
                                         const float* lcoef,
                                         const float* __restrict__ bias) {
  const int cnt = ohi - olo;
  for (int o = t; o < cnt * HID; o += 256) {
    const int nl = (o >> 6) + (olo - base), j = o & 63;
    const int n = base + nl;
    float v = linv[nl] * linv[nl] * shw[nl][j];
    if (n > 0)         v += lcoef[nl - 1] * shw[nl - 1][j];
    if (n < NSCAN - 1) v += lcoef[nl]     * shw[nl + 1][j];
    v += bias[j];
    sh[nl][j] = fmaxf(v, 0.f);
  }
}

__global__ __launch_bounds__(256) void k1_gcn(
    const float* __restrict__ x,
    const float* __restrict__ W1, const float* __restrict__ b1,
    const float* __restrict__ W2, const float* __restrict__ b2,
    const float* __restrict__ W3, const float* __restrict__ b3,
    const float* __restrict__ bm2,
    float* __restrict__ ws, float* __restrict__ out) {
  __shared__ float lmask[EXT + 2];
  __shared__ float linv[EXT];
  __shared__ float lcoef[EXT];
  __shared__ float snod[EXT][2];
  __shared__ float sh[EXT][HID];
  __shared__ float shw[EXT][HID];
  __shared__ float sW[HID][HID];
  __shared__ float sred[4][HID];

  const int t = threadIdx.x;
  const int b = blockIdx.x;
  float* partial = ws + WSF_PARTIAL;

  // out = bm2 each call (block 0; k2 atomicAdds on top, graph-ordered)
  if (b == 0 && t < 200) out[t] = bm2[t];

  const int s = b * CHUNK, e = s + CHUNK;
  const int lo3 = max(0, s - 3), hi3 = min(NSCAN, e + 3);
  const int lo2 = max(0, s - 2), hi2 = min(NSCAN, e + 2);
  const int lo1 = max(0, s - 1), hi1 = min(NSCAN, e + 1);
  const int base = lo3;

  // ---- P0: mask window (wave0), trig nodes (wave1, HW f32), W2 (waves2-3) ----
  if (t < EXT + 2) {
    const int gi = base - 1 + t;
    lmask[t] = (gi >= 0 && gi < NSCAN && x[gi] != 1.0f) ? 1.f : 0.f;
  } else if (t >= 64 && t < 64 + EXT) {
    const int l = t - 64, gi = base + l;
    if (gi < hi3) {
      const float lv = x[gi];
      const float a = (float)((double)gi * (6.283185307179586476925287 / 359.0));
      snod[l][0] = lv * __cosf(a);
      snod[l][1] = lv * __sinf(a);
    }
  }
  if (t >= 128) {
    const float4* src = reinterpret_cast<const float4*>(W2);
    float4* dst = reinterpret_cast<float4*>(&sW[0][0]);
    for (int i = t - 128; i < 1024; i += 128) dst[i] = src[i];
  }
  __syncthreads();

  // ---- P1: inv -> coef (wave0) ; layer-1 matmul (waves 1-3) ----
  if (t < 64) {
    if (t < EXT && base + t < hi3) {
      const float m = lmask[t + 1];
      const float deg = m * (1.f + lmask[t] + lmask[t + 2]);
      linv[t] = (deg > 0.f) ? 1.0f / sqrtf(deg) : 0.f;
    }
    __builtin_amdgcn_wave_barrier();
    if (t < EXT - 1 && base + t < min(NSCAN - 1, hi3 - 1)) {
      const float pair = lmask[t + 1] * lmask[t + 2];
      lcoef[t] = pair * linv[t] * linv[t + 1];
    }
  } else {
    for (int o = t - 64; o < (hi3 - lo3) * HID; o += 192) {
      const int nl = o >> 6, j = o & 63;
      shw[nl][j] = fmaf(snod[nl][0], W1[j], snod[nl][1] * W1[HID + j]);
    }
  }
  __syncthreads();

  agg_relu(t, lo2, hi2, base, shw, sh, linv, lcoef, b1);
  __syncthreads();
  matmul64(t, lo2, hi2, base, sh, shw, sW);
  __syncthreads();
  agg_relu(t, lo1, hi1, base, shw, sh, linv, lcoef, b2);
  {
    const float4* src = reinterpret_cast<const float4*>(W3);
    float4* dst = reinterpret_cast<float4*>(&sW[0][0]);
    for (int i = t; i < 1024; i += 256) dst[i] = src[i];
  }
  __syncthreads();
  matmul64(t, lo1, hi1, base, sh, shw, sW);
  __syncthreads();
  agg_relu(t, s, e, base, shw, sh, linv, lcoef, b3);
  __syncthreads();

  // ---- masked pool over own chunk + per-block mask count ----
  {
    const int jl = t & 63, g = t >> 6;
    float acc = 0.f;
    for (int n = s + g; n < e; n += 4)
      acc += sh[n - base][jl] * lmask[n - base + 1];
    sred[g][jl] = acc;
  }
  __syncthreads();
  if (t < HID)
    partial[b * HID + t] = sred[0][t] + sred[1][t] + sred[2][t] + sred[3][t];
  if (t == 0) {
    float cs = 0.f;
#pragma unroll
    for (int i = 0; i < CHUNK; ++i) cs += lmask[s - base + 1 + i];
    ws[WSF_CNT + b] = cs;
  }
}

__global__ __launch_bounds__(256) void k2_mlp(
    const float* __restrict__ Wp, const float* __restrict__ bp,
    const float* __restrict__ Wm1, const float* __restrict__ bm1,
    const float* __restrict__ Wm2,
    const float* __restrict__ ws, float* __restrict__ out) {
  __shared__ float sgemb[HID];
  __shared__ float sc[512];
  __shared__ float4 swred[4][4];
  __shared__ float sm1[16];

  const int t = threadIdx.x;
  const int b = blockIdx.x;
  const float* partial = ws + WSF_PARTIAL;
  const float* cnt     = ws + WSF_CNT;

  // ---- top prefetches (independent of gemb; overlap everything) ----
  float wv[16];
  if (t < 200) {
#pragma unroll
    for (int rr = 0; rr < 16; ++rr) wv[rr] = Wm2[(b * 16 + rr) * 200 + t];
  }
  const float bp0 = bp[t], bp1 = bp[t + 256];
  float4 bb4 = {0.f, 0.f, 0.f, 0.f};
  if (t < 4) bb4 = reinterpret_cast<const float4*>(bm1)[b * 4 + t];

  // ---- wave0: gemb + n_valid (cnt produced by k1) ----
  if (t < 64) {
    float gsum = 0.f;
#pragma unroll
    for (int bb = 0; bb < NB1; ++bb) gsum += partial[bb * HID + t];
    float cv = (t < NB1) ? cnt[t] : 0.f;
    for (int off = 32; off; off >>= 1) cv += __shfl_down(cv, off, 64);
    const float nv = __shfl(cv, 0, 64);
    sgemb[t] = gsum / nv;
  }
  __syncthreads();

  // ---- c = gemb @ Wp + bp (direct global, coalesced per-k rows) ----
  {
    float acc0 = bp0, acc1 = bp1;
#pragma unroll 16
    for (int k = 0; k < HID; ++k) {
      const float ge = sgemb[k];
      acc0 = fmaf(ge, Wp[k * 512 + t], acc0);
      acc1 = fmaf(ge, Wp[k * 512 + t + 256], acc1);
    }
    sc[t] = acc0;
    sc[t + 256] = acc1;
  }
  __syncthreads();

  // ---- m1 slice: 16 cols (4 float4-chunks), k split over 64 groups ----
  {
    const int c4 = t & 3;          // float4 col chunk
    const int g  = t >> 2;         // 64 k-groups of 8
    const float4* wvv = reinterpret_cast<const float4*>(Wm1) + b * 4 + c4;
    float4 a4; a4.x = 0.f; a4.y = 0.f; a4.z = 0.f; a4.w = 0.f;
    const int k0 = g * 8;
#pragma unroll 8
    for (int ki = 0; ki < 8; ++ki) {
      const float cvv = sc[k0 + ki];
      const float4 w = wvv[(k0 + ki) * 256];
      a4.x = fmaf(cvv, w.x, a4.x);
      a4.y = fmaf(cvv, w.y, a4.y);
      a4.z = fmaf(cvv, w.z, a4.z);
      a4.w = fmaf(cvv, w.w, a4.w);
    }
#pragma unroll
    for (int off = 4; off < 64; off <<= 1) {
      a4.x += __shfl_down(a4.x, off, 64);
      a4.y += __shfl_down(a4.y, off, 64);
      a4.z += __shfl_down(a4.z, off, 64);
      a4.w += __shfl_down(a4.w, off, 64);
    }
    if ((t & 63) < 4) swred[t >> 6][t & 63] = a4;
  }
  __syncthreads();
  if (t < 4) {
    float4 v = swred[0][t];
    const float4 v1 = swred[1][t], v2 = swred[2][t], v3 = swred[3][t];
    v.x += v1.x + v2.x + v3.x;
    v.y += v1.y + v2.y + v3.y;
    v.z += v1.z + v2.z + v3.z;
    v.w += v1.w + v2.w + v3.w;
    float4 r;
    r.x = fmaxf(v.x + bb4.x, 0.f);
    r.y = fmaxf(v.y + bb4.y, 0.f);
    r.z = fmaxf(v.z + bb4.z, 0.f);
    r.w = fmaxf(v.w + bb4.w, 0.f);
    reinterpret_cast<float4*>(sm1)[t] = r;
  }
  __syncthreads();

  // ---- out contribution (Wm2 rows already in regs) ----
  if (t < 200) {
    float acc = 0.f;
#pragma unroll
    for (int rr = 0; rr < 16; ++rr) acc = fmaf(sm1[rr], wv[rr], acc);
    atomicAdd(&out[t], acc);
  }
}

extern "C" void kernel_launch(void* const* d_in, const int* in_sizes, int n_in,
                              void* d_out, int out_size, void* d_ws,
                              size_t ws_size, hipStream_t stream) {
  const float* x   = (const float*)d_in[0];
  const float* W1  = (const float*)d_in[1];
  const float* b1  = (const float*)d_in[2];
  const float* W2  = (const float*)d_in[3];
  const float* b2  = (const float*)d_in[4];
  const float* W3  = (const float*)d_in[5];
  const float* b3  = (const float*)d_in[6];
  const float* Wp  = (const float*)d_in[7];
  const float* bp  = (const float*)d_in[8];
  const float* Wm1 = (const float*)d_in[9];
  const float* bm1 = (const float*)d_in[10];
  const float* Wm2 = (const float*)d_in[11];
  const float* bm2 = (const float*)d_in[12];

  float* ws  = (float*)d_ws;
  float* out = (float*)d_out;

  k1_gcn<<<NB1, 256, 0, stream>>>(x, W1, b1, W2, b2, W3, b3, bm2, ws, out);
  k2_mlp<<<NB2, 256, 0, stream>>>(Wp, bp, Wm1, bm1, Wm2, ws, out);
}